// Round 1
// baseline (1788.885 us; speedup 1.0000x reference)
//
#include <hip/hip_runtime.h>

#define NTOK 4096
#define DIM 32
#define NBH 32          // B*H = 4*8
#define NCHUNK 8
#define CHUNK (NTOK / NCHUNK)   // 512
#define TILE 64

// ws layout (floats)
#define KV2_OFF 0
#define KV2_SZ  (NBH * 1024 * 32)          // 1,048,576 floats
#define KV1_OFF (KV2_OFF + KV2_SZ)
#define KV1_SZ  (NBH * 1024)
#define KSUM_OFF (KV1_OFF + KV1_SZ)
#define KSUM_SZ (NBH * 32)
#define VSUM_OFF (KSUM_OFF + KSUM_SZ)
#define VSUM_SZ (NBH * 32)
#define WS_FLOATS (VSUM_OFF + VSUM_SZ)     // 1,083,392

__global__ __launch_bounds__(256) void zero_kernel(float* __restrict__ p, int n4) {
    float4 z = {0.f, 0.f, 0.f, 0.f};
    for (int i = blockIdx.x * blockDim.x + threadIdx.x; i < n4; i += gridDim.x * blockDim.x)
        ((float4*)p)[i] = z;
}

// Phase 1: per (bh, chunk) reduce over n: kv2[d][e][f] += k_d k_e v_f ; kv1[d][f] += k_d v_f ;
// ksum[d] += k_d ; vsum[f] += v_f.  Thread t owns pairs p = 4t..4t+3 (d = t>>3, e = (t&7)*4 + 0..3).
__global__ __launch_bounds__(256) void phase1_kernel(const float* __restrict__ qkv,
                                                     float* __restrict__ ws) {
    const int chunk = blockIdx.x;
    const int bh = blockIdx.y;
    const float* kptr = qkv + (size_t)(NBH + bh) * (NTOK * DIM);
    const float* vptr = qkv + (size_t)(2 * NBH + bh) * (NTOK * DIM);
    float* kv2 = ws + KV2_OFF + (size_t)bh * (1024 * 32);
    float* kv1 = ws + KV1_OFF + bh * 1024;
    float* ksum = ws + KSUM_OFF + bh * 32;
    float* vsum = ws + VSUM_OFF + bh * 32;

    __shared__ float sk[TILE][DIM];
    __shared__ float sv[TILE][DIM];

    const int t = threadIdx.x;
    const int d = t >> 3;
    const int e0 = (t & 7) << 2;

    float acc[4][32];
#pragma unroll
    for (int j = 0; j < 4; ++j)
#pragma unroll
        for (int f = 0; f < 32; ++f) acc[j][f] = 0.f;
    float acc1[4] = {0.f, 0.f, 0.f, 0.f};
    float accs = 0.f;

    const int n0 = chunk * CHUNK;
    for (int nt = 0; nt < CHUNK; nt += TILE) {
        __syncthreads();
        {
            const float4* kg = (const float4*)(kptr + (size_t)(n0 + nt) * DIM);
            const float4* vg = (const float4*)(vptr + (size_t)(n0 + nt) * DIM);
            float4* skf = (float4*)&sk[0][0];
            float4* svf = (float4*)&sv[0][0];
            skf[t] = kg[t];
            skf[t + 256] = kg[t + 256];
            svf[t] = vg[t];
            svf[t + 256] = vg[t + 256];
        }
        __syncthreads();
#pragma unroll 2
        for (int nn = 0; nn < TILE; ++nn) {
            const float kd = sk[nn][d];
            const float4 ke = *(const float4*)&sk[nn][e0];
            float sj[4];
            sj[0] = kd * ke.x; sj[1] = kd * ke.y; sj[2] = kd * ke.z; sj[3] = kd * ke.w;
#pragma unroll
            for (int f4 = 0; f4 < 8; ++f4) {
                const float4 vf = *(const float4*)&sv[nn][f4 * 4];
                const float vv[4] = {vf.x, vf.y, vf.z, vf.w};
#pragma unroll
                for (int j = 0; j < 4; ++j)
#pragma unroll
                    for (int c = 0; c < 4; ++c)
                        acc[j][4 * f4 + c] += sj[j] * vv[c];
            }
            const float4 vq = *(const float4*)&sv[nn][e0];
            acc1[0] += kd * vq.x; acc1[1] += kd * vq.y;
            acc1[2] += kd * vq.z; acc1[3] += kd * vq.w;
            if (t < 64) accs += (t < 32) ? sk[nn][t] : sv[nn][t - 32];
        }
    }

    // flush partials (8-way contention per address across chunk-blocks)
#pragma unroll
    for (int j = 0; j < 4; ++j) {
        float* dst = kv2 + (size_t)(4 * t + j) * 32;
#pragma unroll
        for (int f = 0; f < 32; ++f) atomicAdd(dst + f, acc[j][f]);
    }
#pragma unroll
    for (int j = 0; j < 4; ++j) atomicAdd(kv1 + d * 32 + e0 + j, acc1[j]);
    if (t < 32) atomicAdd(ksum + t, accs);
    else if (t < 64) atomicAdd(vsum + (t - 32), accs);
}

// Phase 2: one thread per token n. y_f = vsum_f + sum_d q_d kv1[d][f]
//   + sum_{d<e} q_d q_e kv2[d][e][f] + 0.5 sum_d q_d^2 kv2[d][d][f];  y /= (0.5 qk^2 + qk + 1).
// kv2/kv1/ksum/vsum addresses are wave-uniform -> scalar loads feed v_fmac's SGPR operand.
__global__ __launch_bounds__(256) void phase2_kernel(const float* __restrict__ qkv,
                                                     const float* __restrict__ ws,
                                                     float* __restrict__ out) {
    const int bh = blockIdx.y;
    const int n = blockIdx.x * 256 + threadIdx.x;
    const float* qptr = qkv + (size_t)bh * (NTOK * DIM) + (size_t)n * DIM;
    const float* kv2 = ws + KV2_OFF + (size_t)bh * (1024 * 32);
    const float* kv1 = ws + KV1_OFF + bh * 1024;
    const float* ksum = ws + KSUM_OFF + bh * 32;
    const float* vsum = ws + VSUM_OFF + bh * 32;

    float q[32];
#pragma unroll
    for (int i = 0; i < 8; ++i) {
        const float4 t4 = *(const float4*)(qptr + 4 * i);
        q[4 * i + 0] = t4.x; q[4 * i + 1] = t4.y;
        q[4 * i + 2] = t4.z; q[4 * i + 3] = t4.w;
    }

    float y[32];
#pragma unroll
    for (int f = 0; f < 32; ++f) y[f] = vsum[f];

    // kv1 term
#pragma unroll
    for (int dd = 0; dd < 32; ++dd) {
        const float qd = q[dd];
        const float* row = kv1 + dd * 32;
#pragma unroll
        for (int f = 0; f < 32; ++f) y[f] += qd * row[f];
    }

    // kv2 term, symmetric upper triangle (all indices compile-time -> registers + s_loads)
#pragma unroll
    for (int dd = 0; dd < 32; ++dd) {
#pragma unroll
        for (int ee = dd; ee < 32; ++ee) {
            const float s = (ee == dd) ? 0.5f * q[dd] * q[dd] : q[dd] * q[ee];
            const float* row = kv2 + (size_t)(dd * 32 + ee) * 32;
#pragma unroll
            for (int f = 0; f < 32; ++f) y[f] += s * row[f];
        }
    }

    float qk = 0.f;
#pragma unroll
    for (int dd = 0; dd < 32; ++dd) qk += q[dd] * ksum[dd];
    const float ynorm = 0.5f * qk * qk + qk + 1.0f;
    const float inv = 1.0f / ynorm;

    float* optr = out + (size_t)bh * (NTOK * DIM) + (size_t)n * DIM;
#pragma unroll
    for (int i = 0; i < 8; ++i) {
        float4 o;
        o.x = y[4 * i + 0] * inv; o.y = y[4 * i + 1] * inv;
        o.z = y[4 * i + 2] * inv; o.w = y[4 * i + 3] * inv;
        *(float4*)(optr + 4 * i) = o;
    }
}

extern "C" void kernel_launch(void* const* d_in, const int* in_sizes, int n_in,
                              void* d_out, int out_size, void* d_ws, size_t ws_size,
                              hipStream_t stream) {
    const float* qkv = (const float*)d_in[0];
    float* out = (float*)d_out;
    float* ws = (float*)d_ws;

    zero_kernel<<<dim3(512), dim3(256), 0, stream>>>(ws, WS_FLOATS / 4);
    phase1_kernel<<<dim3(NCHUNK, NBH), dim3(256), 0, stream>>>(qkv, ws);
    phase2_kernel<<<dim3(NTOK / 256, NBH), dim3(256), 0, stream>>>(qkv, ws, out);
}

// Round 2
// 307.204 us; speedup vs baseline: 5.8231x; 5.8231x over previous
//
#include <hip/hip_runtime.h>

#define NTOK 4096
#define DIM 32
#define NBH 32          // B*H = 4*8

// slot layout (floats) — slot 0 is the final accumulator, slots 1..nch are per-chunk partials
#define KV2_OFF 0
#define KV2_SZ  (NBH * 1024 * 32)          // 1,048,576 floats
#define KV1_OFF (KV2_OFF + KV2_SZ)
#define KV1_SZ  (NBH * 1024)
#define KSUM_OFF (KV1_OFF + KV1_SZ)
#define KSUM_SZ (NBH * 32)
#define VSUM_OFF (KSUM_OFF + KSUM_SZ)
#define VSUM_SZ (NBH * 32)
#define SLOT (VSUM_OFF + VSUM_SZ)          // 1,083,392 floats
#define TILE 64

__global__ __launch_bounds__(256) void zero_kernel(float* __restrict__ p, int n4) {
    float4 z = {0.f, 0.f, 0.f, 0.f};
    for (int i = blockIdx.x * blockDim.x + threadIdx.x; i < n4; i += gridDim.x * blockDim.x)
        ((float4*)p)[i] = z;
}

// Phase 1: per (bh, chunk): kv2[d][e][f] += k_d k_e v_f ; kv1[d][f] += k_d v_f ; ksum; vsum.
// Thread t owns 4 (d,e) pairs: d = t>>3, e = (t&7)*4 .. +3.
// ATOMIC=false: store partials to slot (1+chunk). ATOMIC=true: atomicAdd into slot 0.
template <bool ATOMIC>
__global__ __launch_bounds__(256) void phase1_kernel(const float* __restrict__ qkv,
                                                     float* __restrict__ ws) {
    const int chunk = blockIdx.x;
    const int bh = blockIdx.y;
    const int CH = NTOK / gridDim.x;
    const float* kptr = qkv + (size_t)(NBH + bh) * (NTOK * DIM);
    const float* vptr = qkv + (size_t)(2 * NBH + bh) * (NTOK * DIM);

    float* base = ATOMIC ? ws : ws + (size_t)SLOT * (1 + chunk);
    float* kv2 = base + KV2_OFF + (size_t)bh * (1024 * 32);
    float* kv1 = base + KV1_OFF + bh * 1024;
    float* ksum = base + KSUM_OFF + bh * 32;
    float* vsum = base + VSUM_OFF + bh * 32;

    __shared__ float sk[TILE][DIM];
    __shared__ float sv[TILE][DIM];

    const int t = threadIdx.x;
    const int d = t >> 3;
    const int e0 = (t & 7) << 2;

    float acc[4][32];
#pragma unroll
    for (int j = 0; j < 4; ++j)
#pragma unroll
        for (int f = 0; f < 32; ++f) acc[j][f] = 0.f;
    float acc1[4] = {0.f, 0.f, 0.f, 0.f};
    float accs = 0.f;

    const int n0 = chunk * CH;
    for (int nt = 0; nt < CH; nt += TILE) {
        __syncthreads();
        {
            const float4* kg = (const float4*)(kptr + (size_t)(n0 + nt) * DIM);
            const float4* vg = (const float4*)(vptr + (size_t)(n0 + nt) * DIM);
            float4* skf = (float4*)&sk[0][0];
            float4* svf = (float4*)&sv[0][0];
            skf[t] = kg[t];
            skf[t + 256] = kg[t + 256];
            svf[t] = vg[t];
            svf[t + 256] = vg[t + 256];
        }
        __syncthreads();
#pragma unroll 2
        for (int nn = 0; nn < TILE; ++nn) {
            const float kd = sk[nn][d];
            const float4 ke = *(const float4*)&sk[nn][e0];
            float sj[4];
            sj[0] = kd * ke.x; sj[1] = kd * ke.y; sj[2] = kd * ke.z; sj[3] = kd * ke.w;
#pragma unroll
            for (int f4 = 0; f4 < 8; ++f4) {
                const float4 vf = *(const float4*)&sv[nn][f4 * 4];
                const float vv[4] = {vf.x, vf.y, vf.z, vf.w};
#pragma unroll
                for (int j = 0; j < 4; ++j)
#pragma unroll
                    for (int c = 0; c < 4; ++c)
                        acc[j][4 * f4 + c] += sj[j] * vv[c];
            }
            const float4 vq = *(const float4*)&sv[nn][e0];
            acc1[0] += kd * vq.x; acc1[1] += kd * vq.y;
            acc1[2] += kd * vq.z; acc1[3] += kd * vq.w;
            if (t < 64) accs += (t < 32) ? sk[nn][t] : sv[nn][t - 32];
        }
    }

#pragma unroll
    for (int j = 0; j < 4; ++j) {
        float* dst = kv2 + (size_t)(4 * t + j) * 32;
        if (ATOMIC) {
#pragma unroll
            for (int f = 0; f < 32; ++f) atomicAdd(dst + f, acc[j][f]);
        } else {
#pragma unroll
            for (int f4 = 0; f4 < 8; ++f4) {
                float4 v;
                v.x = acc[j][4 * f4 + 0]; v.y = acc[j][4 * f4 + 1];
                v.z = acc[j][4 * f4 + 2]; v.w = acc[j][4 * f4 + 3];
                *(float4*)(dst + 4 * f4) = v;
            }
        }
    }
    if (ATOMIC) {
#pragma unroll
        for (int j = 0; j < 4; ++j) atomicAdd(kv1 + d * 32 + e0 + j, acc1[j]);
        if (t < 32) atomicAdd(ksum + t, accs);
        else if (t < 64) atomicAdd(vsum + (t - 32), accs);
    } else {
        float4 v1; v1.x = acc1[0]; v1.y = acc1[1]; v1.z = acc1[2]; v1.w = acc1[3];
        *(float4*)(kv1 + d * 32 + e0) = v1;
        if (t < 32) ksum[t] = accs;
        else if (t < 64) vsum[t - 32] = accs;
    }
}

// Sum partial slots 1..nch into slot 0.
__global__ __launch_bounds__(256) void reduce_kernel(float* __restrict__ ws, int nch) {
    const int i = blockIdx.x * 256 + threadIdx.x;   // float4 index
    if (i >= SLOT / 4) return;
    float4 a = {0.f, 0.f, 0.f, 0.f};
    for (int c = 1; c <= nch; ++c) {
        const float4 p = ((const float4*)(ws + (size_t)SLOT * c))[i];
        a.x += p.x; a.y += p.y; a.z += p.z; a.w += p.w;
    }
    ((float4*)ws)[i] = a;
}

// Phase 2: lane = token, f = register index, w-rows wave-uniform (scalar-load friendly),
// q accessed through transposed LDS so all loops stay ROLLED (small body, low VGPR).
__global__ __launch_bounds__(256) void phase2_kernel(const float* __restrict__ qkv,
                                                     const float* __restrict__ ws,
                                                     float* __restrict__ out) {
    const int bh = blockIdx.y;
    const int t = threadIdx.x;
    const int tok0 = blockIdx.x * 256;
    const float* qptr = qkv + (size_t)bh * (NTOK * DIM) + (size_t)tok0 * DIM;
    const float* kv2 = ws + KV2_OFF + (size_t)bh * (1024 * 32);
    const float* kv1 = ws + KV1_OFF + bh * 1024;
    const float* ksum = ws + KSUM_OFF + bh * 32;
    const float* vsum = ws + VSUM_OFF + bh * 32;

    __shared__ float qT[32][256];
    {
        const float4* q4 = (const float4*)qptr + t * 8;
#pragma unroll
        for (int i = 0; i < 8; ++i) {
            const float4 v = q4[i];
            qT[4 * i + 0][t] = v.x; qT[4 * i + 1][t] = v.y;
            qT[4 * i + 2][t] = v.z; qT[4 * i + 3][t] = v.w;
        }
    }
    __syncthreads();

    float y[32];
#pragma unroll
    for (int f4 = 0; f4 < 8; ++f4) {
        const float4 v = ((const float4*)vsum)[f4];
        y[4 * f4 + 0] = v.x; y[4 * f4 + 1] = v.y;
        y[4 * f4 + 2] = v.z; y[4 * f4 + 3] = v.w;
    }
    float qk = 0.f;

    // kv1 term + qk
#pragma unroll 1
    for (int d = 0; d < 32; ++d) {
        const float qd = qT[d][t];
        qk += qd * ksum[d];
        const float4* r = (const float4*)(kv1 + d * 32);
#pragma unroll
        for (int f4 = 0; f4 < 8; ++f4) {
            const float4 w = r[f4];
            y[4 * f4 + 0] += qd * w.x; y[4 * f4 + 1] += qd * w.y;
            y[4 * f4 + 2] += qd * w.z; y[4 * f4 + 3] += qd * w.w;
        }
    }

    // kv2 triangle: diag (0.5 q_d^2) + off-diag (q_d q_e), rows wave-uniform
#pragma unroll 1
    for (int d = 0; d < 32; ++d) {
        const float qd = qT[d][t];
        {
            const float s = 0.5f * qd * qd;
            const float4* r = (const float4*)(kv2 + (size_t)(d * 32 + d) * 32);
#pragma unroll
            for (int f4 = 0; f4 < 8; ++f4) {
                const float4 w = r[f4];
                y[4 * f4 + 0] += s * w.x; y[4 * f4 + 1] += s * w.y;
                y[4 * f4 + 2] += s * w.z; y[4 * f4 + 3] += s * w.w;
            }
        }
#pragma unroll 1
        for (int e = d + 1; e < 32; ++e) {
            const float s = qd * qT[e][t];
            const float4* r = (const float4*)(kv2 + (size_t)(d * 32 + e) * 32);
#pragma unroll
            for (int f4 = 0; f4 < 8; ++f4) {
                const float4 w = r[f4];
                y[4 * f4 + 0] += s * w.x; y[4 * f4 + 1] += s * w.y;
                y[4 * f4 + 2] += s * w.z; y[4 * f4 + 3] += s * w.w;
            }
        }
    }

    const float inv = 1.0f / (0.5f * qk * qk + qk + 1.0f);
    float4* o4 = (float4*)(out + (size_t)bh * (NTOK * DIM) + (size_t)(tok0 + t) * DIM);
#pragma unroll
    for (int f4 = 0; f4 < 8; ++f4) {
        float4 v;
        v.x = y[4 * f4 + 0] * inv; v.y = y[4 * f4 + 1] * inv;
        v.z = y[4 * f4 + 2] * inv; v.w = y[4 * f4 + 3] * inv;
        o4[f4] = v;
    }
}

extern "C" void kernel_launch(void* const* d_in, const int* in_sizes, int n_in,
                              void* d_out, int out_size, void* d_ws, size_t ws_size,
                              hipStream_t stream) {
    const float* qkv = (const float*)d_in[0];
    float* out = (float*)d_out;
    float* ws = (float*)d_ws;

    // how many partial slots fit? (slot 0 = final, slots 1..nch = partials)
    const size_t slot_bytes = (size_t)SLOT * 4;
    int avail = (int)(ws_size / slot_bytes) - 1;
    int nch = 0;
    if (avail >= 16) nch = 16;
    else if (avail >= 8) nch = 8;
    else if (avail >= 4) nch = 4;
    else if (avail >= 2) nch = 2;

    if (nch > 0) {
        phase1_kernel<false><<<dim3(nch, NBH), dim3(256), 0, stream>>>(qkv, ws);
        reduce_kernel<<<dim3(SLOT / 4 / 256), dim3(256), 0, stream>>>(ws, nch);
    } else {
        zero_kernel<<<dim3(512), dim3(256), 0, stream>>>(ws, SLOT / 4);
        phase1_kernel<true><<<dim3(8, NBH), dim3(256), 0, stream>>>(qkv, ws);
    }
    phase2_kernel<<<dim3(NTOK / 256, NBH), dim3(256), 0, stream>>>(qkv, ws, out);
}

// Round 3
// 184.164 us; speedup vs baseline: 9.7135x; 1.6681x over previous
//
#include <hip/hip_runtime.h>

#define NTOK 4096
#define DIM 32
#define NBH 32              // B*H
#define NPAIR2 528          // upper triangle incl. diagonal of 32x32
#define NROWS 560           // + 32 kv1 rows
#define BHF (NROWS * 32 + 64)       // floats per bh: rows + ksum(32) + vsum(32) = 17984
#define SLOT (NBH * BHF)            // 575488 floats per slot (2.30 MB)
#define TILE 64
#define LSTR 36             // padded LDS row stride (16B-aligned, col 32 holds 1.0)

__device__ __forceinline__ int tri_start(int d) { return (d * (65 - d)) >> 1; }

__device__ __forceinline__ int tri_decode_d(int p) {
    int d = (int)((65.0f - sqrtf((float)(4225 - 8 * p))) * 0.5f);
    if (d < 0) d = 0;
    if (d > 31) d = 31;
    while (d < 31 && tri_start(d + 1) <= p) ++d;
    while (d > 0 && tri_start(d) > p) --d;
    return d;
}

// Phase 1: per (bh, chunk) partial sums of the NROWS weight rows.
// Row p < 528: (d,e) triangle pair, w[p][f] = sum_n k_d k_e v_f.
// Row 528+d:   kv1, w[f] = sum_n k_d v_f  (via pad column = 1.0).
// ksum/vsum computed by wave 3 lanes.
__global__ __launch_bounds__(256) void phase1_kernel(const float* __restrict__ qkv,
                                                     float* __restrict__ ws, int direct) {
    const int chunk = blockIdx.x;
    const int nch = gridDim.x;
    const int bh = blockIdx.y;
    const int CH = NTOK / nch;
    const int t = threadIdx.x;
    const float* kptr = qkv + (size_t)(NBH + bh) * (NTOK * DIM);
    const float* vptr = qkv + (size_t)(2 * NBH + bh) * (NTOK * DIM);
    float* base = ws + (direct ? (size_t)0 : (size_t)SLOT * (1 + chunk)) + (size_t)bh * BHF;

    __shared__ __align__(16) float sk[TILE][LSTR];
    __shared__ __align__(16) float sv[TILE][LSTR];

    // pair index setup: p0 = t (kv2), p1 = t+256 (kv2), p2 = 512+t for t<48 (kv2 or kv1)
    int ia0, ib0, ia1, ib1, ia2 = 0, ib2 = 0;
    {
        int d = tri_decode_d(t);
        ia0 = d; ib0 = d + (t - tri_start(d));
        int p1 = t + 256;
        d = tri_decode_d(p1);
        ia1 = d; ib1 = d + (p1 - tri_start(d));
        if (t < 48) {
            int p2 = 512 + t;
            if (p2 < NPAIR2) { d = tri_decode_d(p2); ia2 = d; ib2 = d + (p2 - tri_start(d)); }
            else { ia2 = p2 - NPAIR2; ib2 = 32; }   // kv1 row: s = k_d * 1.0
        }
    }
    const float* a0p = &sk[0][ia0];
    const float* b0p = &sk[0][ib0];
    const float* a1p = &sk[0][ia1];
    const float* b1p = &sk[0][ib1];
    const float* a2p = &sk[0][ia2];
    const float* b2p = &sk[0][ib2];
    // wave-3 running-sum source: lanes 192..223 -> k column, 224..255 -> v column
    const float* sump = (t >= 224) ? &sv[0][t - 224] : &sk[0][(t >= 192) ? (t - 192) : 0];

    float acc0[32], acc1[32], acc2[32];
#pragma unroll
    for (int f = 0; f < 32; ++f) { acc0[f] = 0.f; acc1[f] = 0.f; acc2[f] = 0.f; }
    float accs = 0.f;

    const int n0 = chunk * CH;
    for (int nt = 0; nt < CH; nt += TILE) {
        __syncthreads();
        {
            const float4* kg4 = (const float4*)(kptr + (size_t)(n0 + nt) * DIM);
            const float4* vg4 = (const float4*)(vptr + (size_t)(n0 + nt) * DIM);
            const int i0 = t, i1 = t + 256;
            *(float4*)&sk[i0 >> 3][(i0 & 7) << 2] = kg4[i0];
            *(float4*)&sk[i1 >> 3][(i1 & 7) << 2] = kg4[i1];
            *(float4*)&sv[i0 >> 3][(i0 & 7) << 2] = vg4[i0];
            *(float4*)&sv[i1 >> 3][(i1 & 7) << 2] = vg4[i1];
            if (t >= 64 && t < 128) sk[t - 64][32] = 1.0f;  // pad col: 1.0 for kv1 rows
        }
        __syncthreads();
#pragma unroll 2
        for (int nn = 0; nn < TILE; ++nn) {
            const int off = nn * LSTR;
            const float s0 = a0p[off] * b0p[off];
            const float s1 = a1p[off] * b1p[off];
            float4 vv[8];
#pragma unroll
            for (int f4 = 0; f4 < 8; ++f4) vv[f4] = *(const float4*)&sv[nn][f4 << 2];
#pragma unroll
            for (int f4 = 0; f4 < 8; ++f4) {
                acc0[4 * f4 + 0] += s0 * vv[f4].x; acc0[4 * f4 + 1] += s0 * vv[f4].y;
                acc0[4 * f4 + 2] += s0 * vv[f4].z; acc0[4 * f4 + 3] += s0 * vv[f4].w;
                acc1[4 * f4 + 0] += s1 * vv[f4].x; acc1[4 * f4 + 1] += s1 * vv[f4].y;
                acc1[4 * f4 + 2] += s1 * vv[f4].z; acc1[4 * f4 + 3] += s1 * vv[f4].w;
            }
            if (t < 48) {
                const float s2 = a2p[off] * b2p[off];
#pragma unroll
                for (int f4 = 0; f4 < 8; ++f4) {
                    acc2[4 * f4 + 0] += s2 * vv[f4].x; acc2[4 * f4 + 1] += s2 * vv[f4].y;
                    acc2[4 * f4 + 2] += s2 * vv[f4].z; acc2[4 * f4 + 3] += s2 * vv[f4].w;
                }
            }
            if (t >= 192) accs += sump[off];
        }
    }

    // flush rows
    float* dst0 = base + (size_t)t * 32;
    float* dst1 = base + (size_t)(t + 256) * 32;
#pragma unroll
    for (int j = 0; j < 8; ++j) {
        float4 v; v.x = acc0[4 * j]; v.y = acc0[4 * j + 1]; v.z = acc0[4 * j + 2]; v.w = acc0[4 * j + 3];
        ((float4*)dst0)[j] = v;
    }
#pragma unroll
    for (int j = 0; j < 8; ++j) {
        float4 v; v.x = acc1[4 * j]; v.y = acc1[4 * j + 1]; v.z = acc1[4 * j + 2]; v.w = acc1[4 * j + 3];
        ((float4*)dst1)[j] = v;
    }
    if (t < 48) {
        float* dst2 = base + (size_t)(512 + t) * 32;
#pragma unroll
        for (int j = 0; j < 8; ++j) {
            float4 v; v.x = acc2[4 * j]; v.y = acc2[4 * j + 1]; v.z = acc2[4 * j + 2]; v.w = acc2[4 * j + 3];
            ((float4*)dst2)[j] = v;
        }
    }
    if (t >= 192) base[NROWS * 32 + (t - 192)] = accs;  // ksum (0..31) then vsum (32..63)
}

// Sum partial slots 1..nch into slot 0.
__global__ __launch_bounds__(256) void reduce_kernel(float* __restrict__ ws, int nch) {
    const int i = blockIdx.x * 256 + threadIdx.x;
    if (i >= SLOT / 4) return;
    float4 a = {0.f, 0.f, 0.f, 0.f};
    for (int c = 1; c <= nch; ++c) {
        const float4 p = ((const float4*)(ws + (size_t)SLOT * c))[i];
        a.x += p.x; a.y += p.y; a.z += p.z; a.w += p.w;
    }
    ((float4*)ws)[i] = a;
}

// Phase 2: lane = token, 16 of 32 f per block (blockIdx.z), rows walked consecutively,
// e-loop unrolled x4 so the wave-uniform row loads pipeline ahead of the fmacs.
__global__ __launch_bounds__(256) void phase2_kernel(const float* __restrict__ qkv,
                                                     const float* __restrict__ ws,
                                                     float* __restrict__ out) {
    const int bh = blockIdx.y;
    const int f0 = blockIdx.z << 4;
    const int t = threadIdx.x;
    const int tok0 = blockIdx.x * 256;
    const float* qptr = qkv + (size_t)bh * (NTOK * DIM) + (size_t)tok0 * DIM;
    const float* base = ws + (size_t)bh * BHF;
    const float* ksum = base + NROWS * 32;
    const float* vsum = ksum + 32;

    __shared__ float qT[32][256];
    {
        const float4* q4 = (const float4*)qptr + (size_t)t * 8;
#pragma unroll
        for (int i = 0; i < 8; ++i) {
            const float4 v = q4[i];
            qT[4 * i + 0][t] = v.x; qT[4 * i + 1][t] = v.y;
            qT[4 * i + 2][t] = v.z; qT[4 * i + 3][t] = v.w;
        }
    }
    __syncthreads();

    float y[16];
#pragma unroll
    for (int j = 0; j < 4; ++j) {
        const float4 v = *(const float4*)(vsum + f0 + 4 * j);
        y[4 * j + 0] = v.x; y[4 * j + 1] = v.y; y[4 * j + 2] = v.z; y[4 * j + 3] = v.w;
    }
    float qk = 0.f;

    const float* rowp = base + f0;   // walks the 528 triangle rows, then 32 kv1 rows
#pragma unroll 1
    for (int d = 0; d < 32; ++d) {
        const float qd = qT[d][t];
        qk += qd * ksum[d];
        {   // diagonal row (e == d): s = 0.5 qd^2
            const float s = 0.5f * qd * qd;
            const float4* r = (const float4*)rowp;
#pragma unroll
            for (int j = 0; j < 4; ++j) {
                const float4 w = r[j];
                y[4 * j + 0] += s * w.x; y[4 * j + 1] += s * w.y;
                y[4 * j + 2] += s * w.z; y[4 * j + 3] += s * w.w;
            }
            rowp += 32;
        }
#pragma unroll 4
        for (int e = d + 1; e < 32; ++e) {
            const float s = qd * qT[e][t];
            const float4* r = (const float4*)rowp;
#pragma unroll
            for (int j = 0; j < 4; ++j) {
                const float4 w = r[j];
                y[4 * j + 0] += s * w.x; y[4 * j + 1] += s * w.y;
                y[4 * j + 2] += s * w.z; y[4 * j + 3] += s * w.w;
            }
            rowp += 32;
        }
    }
    // kv1 rows
#pragma unroll 4
    for (int d = 0; d < 32; ++d) {
        const float qd = qT[d][t];
        const float4* r = (const float4*)rowp;
#pragma unroll
        for (int j = 0; j < 4; ++j) {
            const float4 w = r[j];
            y[4 * j + 0] += qd * w.x; y[4 * j + 1] += qd * w.y;
            y[4 * j + 2] += qd * w.z; y[4 * j + 3] += qd * w.w;
        }
        rowp += 32;
    }

    const float inv = 1.0f / (0.5f * qk * qk + qk + 1.0f);
    float4* o4 = (float4*)(out + (size_t)bh * (NTOK * DIM) + (size_t)(tok0 + t) * DIM + f0);
#pragma unroll
    for (int j = 0; j < 4; ++j) {
        float4 v;
        v.x = y[4 * j + 0] * inv; v.y = y[4 * j + 1] * inv;
        v.z = y[4 * j + 2] * inv; v.w = y[4 * j + 3] * inv;
        o4[j] = v;
    }
}

extern "C" void kernel_launch(void* const* d_in, const int* in_sizes, int n_in,
                              void* d_out, int out_size, void* d_ws, size_t ws_size,
                              hipStream_t stream) {
    const float* qkv = (const float*)d_in[0];
    float* out = (float*)d_out;
    float* ws = (float*)d_ws;

    const size_t slot_bytes = (size_t)SLOT * 4;
    const int avail = (int)(ws_size / slot_bytes) - 1;  // partial slots available
    int nch = 32;
    while (nch > 1 && avail < nch) nch >>= 1;

    if (nch >= 2) {
        phase1_kernel<<<dim3(nch, NBH), dim3(256), 0, stream>>>(qkv, ws, 0);
        reduce_kernel<<<dim3(SLOT / 4 / 256), dim3(256), 0, stream>>>(ws, nch);
    } else {
        phase1_kernel<<<dim3(1, NBH), dim3(256), 0, stream>>>(qkv, ws, 1);
    }
    phase2_kernel<<<dim3(NTOK / 256, NBH, 2), dim3(256), 0, stream>>>(qkv, ws, out);
}